// Round 4
// baseline (115.808 us; speedup 1.0000x reference)
//
#include <hip/hip_runtime.h>
#include <math.h>

// ---------------- problem constants ----------------
#define PATCH   11
#define PP      121          // PATCH*PATCH
#define NPX     35           // (80-11)/2+1 patches per row/col
#define NPATCH  1225         // per image
#define P2      2450         // x-patches + y-patches
#define NC      3
#define NB      2
#define NROW    2560         // padded rows: 20 strips of 128
#define NKC     16           // K=128 as 16 chunks of 8 halfs
#define RT      128          // rows per strip (A side per block)
#define CT      64           // cols per block (B side)
#define NSTRIP  (NROW/RT)    // 20
#define NCT     (NROW/CT)    // 40
#define C1f     1.0e-4f      // 0.01^2
#define C2f     9.0e-4f      // 0.03^2

typedef _Float16 f16;
typedef __attribute__((ext_vector_type(8)))  _Float16 f16x8;
typedef __attribute__((ext_vector_type(16))) float    f32x16;

// ---------------------------------------------------------------------------
// Kernel 1: patch extraction directly into MFMA-fragment-native layout:
//   Zh/Zl[b][c][kc=0..15][row=0..NROW-1][8 halfs]   (16B per (kc,row))
//   msig[b][c][row] = {mu^2, sigma}
// One thread per (row, kc): computes 8 window pixels, stores one 16B chunk
// (h and l), 16-lane shuffle-reduce for mu / E[X^2].
// ---------------------------------------------------------------------------
__global__ __launch_bounds__(256) void extract_kernel(
        const float* __restrict__ x, const float* __restrict__ y,
        f16* __restrict__ Zh, f16* __restrict__ Zl,
        float2* __restrict__ msig, double* __restrict__ acc) {
    int t = threadIdx.x, lane = t & 63, w = t >> 6;
    int i  = blockIdx.x * 16 + w * 4 + (lane >> 4);   // row
    int kc = lane & 15;                               // 8-half chunk index
    int c = blockIdx.y, b = blockIdx.z;
    if (t == 0 && blockIdx.x == 0 && c == 0 && b == 0) acc[0] = 0.0;

    int bc = b * NC + c;
    bool valid = (i < P2);

    // normalized 1D gaussian (matches _fspecial_gauss_1d in f32)
    float g1[PATCH]; float gs = 0.f;
#pragma unroll
    for (int k = 0; k < PATCH; k++) {
        float d = (float)(k - PATCH / 2);
        g1[k] = expf(-(d * d) / 4.5f);      // 2*sigma^2 = 4.5
        gs += g1[k];
    }
    float inv2 = 1.0f / (gs * gs);

    const float* base = x;
    if (valid) {
        const float* img = (i < NPATCH) ? x : y;
        int ip = (i < NPATCH) ? i : i - NPATCH;
        int py = ip / NPX, px = ip - py * NPX;
        base = img + ((size_t)bc * 80 + py * 2) * 80 + px * 2;
    }

    float mu = 0.f, e2 = 0.f;
    f16x8 hv = {}, lv = {};
#pragma unroll
    for (int q = 0; q < 8; q++) {
        int p = kc * 8 + q;
        float z = 0.f;
        if (valid && p < PP) {
            int r = p / PATCH, s = p - (p / PATCH) * PATCH;
            float wg = g1[r] * g1[s] * inv2;
            float X = (base[r * 80 + s] + 1.0f) * 0.5f;
            mu = fmaf(wg, X, mu);
            e2 = fmaf(wg * X, X, e2);
            z = sqrtf(wg) * X;
        }
        f16 h = (f16)z;
        hv[q] = h;
        lv[q] = (f16)(z - (float)h);
    }
    size_t off = (((size_t)bc * NKC + kc) * NROW + i) * 8;
    *(f16x8*)(Zh + off) = hv;
    *(f16x8*)(Zl + off) = lv;

    // reduce mu,e2 across the 16 lanes of this row (xor within 16-group)
#pragma unroll
    for (int m = 1; m < 16; m <<= 1) {
        mu += __shfl_xor(mu, m);
        e2 += __shfl_xor(e2, m);
    }
    if (kc == 0) {
        float m2 = mu * mu;
        msig[(size_t)bc * NROW + i] = make_float2(m2, e2 - m2);
    }
}

// ---------------------------------------------------------------------------
// Kernel 2: pairwise Gram, NO LDS — MFMA fragments loaded straight from
// global (L1/L2-resident, perfectly coalesced 512B segments per half-wave).
// Block = 128-row strip x 64-col tile, 4 waves; wave w owns rows R0..R0+31
// (Ah resident in 32 VGPRs, reused across 2 col-blocks); Al/Bh/Bl streamed.
// hi/lo f16 split: G = Ah*Bh + Ah*Bl + Al*Bh (error ~2^-22).
// Fused SSIM epilogue per col-block, fp64 block reduce, one atomic.
// ---------------------------------------------------------------------------
__global__ __launch_bounds__(256) void pair_kernel(
        const f16* __restrict__ Zh, const f16* __restrict__ Zl,
        const float2* __restrict__ msig, double* __restrict__ acc) {
    int tj = blockIdx.x, si = blockIdx.y, b = blockIdx.z;
    if (tj < 2 * si) return;          // strictly-below-diagonal tile: skip

    int t = threadIdx.x, lane = t & 63, w = t >> 6;
    int lr = lane & 31, hi = lane >> 5;
    int R0 = si * RT + w * 32;

    double local = 0.0;

    for (int c = 0; c < NC; c++) {
        int bc = b * NC + c;
        const f16* zh = Zh + (size_t)bc * NKC * NROW * 8;
        const f16* zl = Zl + (size_t)bc * NKC * NROW * 8;
        const float2* ms = msig + (size_t)bc * NROW;

        f16x8 Ah[8];
#pragma unroll
        for (int ks = 0; ks < 8; ks++)
            Ah[ks] = *(const f16x8*)(zh + ((size_t)(ks * 2 + hi) * NROW + R0 + lr) * 8);

#pragma unroll
        for (int cb = 0; cb < 2; cb++) {
            int C0 = tj * CT + cb * 32;
            f32x16 a = {};
#pragma unroll
            for (int ks = 0; ks < 8; ks++) {
                size_t ko = (size_t)(ks * 2 + hi) * NROW;
                f16x8 bh = *(const f16x8*)(zh + (ko + C0 + lr) * 8);
                f16x8 bl = *(const f16x8*)(zl + (ko + C0 + lr) * 8);
                f16x8 al = *(const f16x8*)(zl + (ko + R0 + lr) * 8);
                a = __builtin_amdgcn_mfma_f32_32x32x16_f16(Ah[ks], bh, a, 0, 0, 0);
                a = __builtin_amdgcn_mfma_f32_32x32x16_f16(Ah[ks], bl, a, 0, 0, 0);
                a = __builtin_amdgcn_mfma_f32_32x32x16_f16(al,     bh, a, 0, 0, 0);
            }

            // fused SSIM epilogue for this 32x32 quadrant
            int gj = C0 + lr;
            float2 mj = ms[gj];
            bool yj = gj < NPATCH;
#pragma unroll
            for (int reg = 0; reg < 16; reg++) {
                int gi = R0 + (reg & 3) + 8 * (reg >> 2) + 4 * hi;
                float2 mi = ms[gi];
                float mm  = mi.x * mj.x;
                float sxy = a[reg] - mm;
                float num = (2.f * mm + C1f) * (2.f * sxy + C2f);
                float den = (mi.x + mj.x + C1f) * (mi.y + mj.y + C2f);
                float kv  = num * __builtin_amdgcn_rcpf(den);
                float wgt = (gj > gi) ? 2.f : ((gj == gi) ? 1.f : 0.f);
                if (gi >= P2 || gj >= P2) wgt = 0.f;
                float sgn = ((gi < NPATCH) == yj) ? 1.f : -1.f;
                local += (double)(wgt * sgn * kv);
            }
        }
    }

    // block reduction: wave shuffle then cross-wave
#pragma unroll
    for (int off = 32; off > 0; off >>= 1)
        local += __shfl_down(local, off);
    __shared__ double red[4];
    if (lane == 0) red[w] = local;
    __syncthreads();
    if (t == 0)
        atomicAdd(acc, red[0] + red[1] + red[2] + red[3]);
}

// ---------------------------------------------------------------------------
// Kernel 3: final scale:  loss = acc / (B * 3 * 1225^2)
// ---------------------------------------------------------------------------
__global__ void finalize_kernel(const double* __restrict__ acc,
                                float* __restrict__ out) {
    if (threadIdx.x == 0 && blockIdx.x == 0)
        out[0] = (float)(acc[0] * (1.0 / (2.0 * 3.0 * (double)NPATCH * (double)NPATCH)));
}

// ---------------------------------------------------------------------------
extern "C" void kernel_launch(void* const* d_in, const int* in_sizes, int n_in,
                              void* d_out, int out_size, void* d_ws, size_t ws_size,
                              hipStream_t stream) {
    const float* x = (const float*)d_in[0];
    const float* y = (const float*)d_in[1];
    float* out = (float*)d_out;

    // workspace layout (16B aligned): [acc][Zh][Zl][msig]  ~8.0 MB
    double* acc = (double*)d_ws;
    f16* Zh = (f16*)((char*)d_ws + 16);
    size_t zcnt = (size_t)NB * NC * NKC * NROW * 8;   // 1,966,080 halfs
    f16* Zl = Zh + zcnt;
    float2* msig = (float2*)(Zl + zcnt);

    dim3 g1(NROW / 16, NC, NB);
    extract_kernel<<<g1, 256, 0, stream>>>(x, y, Zh, Zl, msig, acc);

    dim3 g2(NCT, NSTRIP, NB);
    pair_kernel<<<g2, 256, 0, stream>>>(Zh, Zl, msig, acc);

    finalize_kernel<<<1, 64, 0, stream>>>(acc, out);
}